// Round 7
// baseline (684.205 us; speedup 1.0000x reference)
//
#include <hip/hip_runtime.h>
#include <hip/hip_bf16.h>
#include <math.h>

#define XN 262144
#define NPAIR (XN - 1)
#define BN 64
#define HD 256
#define KK 8
#define THRC 1e-6f

__device__ __forceinline__ float gelu_f(float x) {
    return 0.5f * x * (1.0f + erff(x * 0.70710678118654752440f));
}

__device__ __forceinline__ unsigned short f2bf(float f) {
    unsigned int x = __float_as_uint(f);
    unsigned int r = (x + 0x7fffu + ((x >> 16) & 1u)) >> 16;  // RNE
    return (unsigned short)r;
}

// ---------------- Kernel 0: weights fp32 -> bf16, TRANSPOSED + lane-blocked --
// Layout per matrix (ushort idx): addr(n,c) = ((n>>6)*NC + c)*512 + (n&63)*8
// where c indexes 8-element K-chunks (NC = K/8). A wave of 64 consecutive
// cols loading chunk c reads 1 KB contiguous -> fully coalesced.
// Regions: [0) rb_w1T i=0..2 (NC=32, N=512, 131072 each) | [393216) rb_w2T
// (NC=64, N=256) | [786432) out_w1T (NC=32, N=128) | end 819200.
__global__ __launch_bounds__(256) void convert_kernel(
    const float* __restrict__ rb_w1, const float* __restrict__ rb_w2,
    const float* __restrict__ out_w1, unsigned short* __restrict__ bw) {
    int t = blockIdx.x * 256 + threadIdx.x;
    const float* s;
    int stride;
    unsigned short* d;
    if (t < 49152) {
        int i = t / 16384, r = t % 16384;
        int c = r >> 9, n = r & 511;  // c in [0,32), n in [0,512)
        s = rb_w1 + (size_t)i * 131072 + (size_t)c * 8 * 512 + n;
        stride = 512;
        d = bw + (size_t)i * 131072 + (((n >> 6) * 32 + c) * 512 + (n & 63) * 8);
    } else if (t < 98304) {
        int t2 = t - 49152;
        int i = t2 / 16384, r = t2 % 16384;
        int c = r >> 8, n = r & 255;  // c in [0,64), n in [0,256)
        s = rb_w2 + (size_t)i * 131072 + (size_t)c * 8 * 256 + n;
        stride = 256;
        d = bw + 393216 + (size_t)i * 131072 +
            (((n >> 6) * 64 + c) * 512 + (n & 63) * 8);
    } else {
        int r = t - 98304;            // [0,4096)
        int c = r >> 7, n = r & 127;  // c in [0,32), n in [0,128)
        s = out_w1 + (size_t)c * 8 * 128 + n;
        stride = 128;
        d = bw + 786432 + (((n >> 6) * 32 + c) * 512 + (n & 63) * 8);
    }
    union { unsigned short u[8]; uint4 v; } rr;
#pragma unroll
    for (int j = 0; j < 8; ++j) rr.u[j] = f2bf(s[j * stride]);
    *(uint4*)d = rr.v;
}

// ---------------- Kernel 1: fused count + first-8 select ---------------------
__global__ __launch_bounds__(256) void count_select_kernel(
    const float* __restrict__ x, float* __restrict__ out,
    float* __restrict__ ws_uLuR, int* __restrict__ ws_cnt) {
    __shared__ int sred[4];
    const int b = blockIdx.x >> 4;
    const int p = blockIdx.x & 15;
    const float* row = x + (size_t)b * 2 * XN;
    const int tid = threadIdx.x;
    const int lane = tid & 63, wave = tid >> 6;

    if (p == 0 && tid < 64) {
        const float* c = row + XN;
        int idxs[KK];
        float vflag[KK];
        int found = 0;
        for (int base = 0; base < NPAIR && found < KK; base += 64) {
            int i = base + lane;
            bool v = (i < NPAIR) && (fabsf(row[i] - row[i + 1]) > THRC);
            unsigned long long m = __ballot(v);
            while (m && found < KK) {
                int l = __ffsll(m) - 1;
                idxs[found] = base + l;
                vflag[found] = 1.0f;
                ++found;
                m &= (m - 1);
            }
        }
        if (found < KK) {
            for (int base = 0; base < NPAIR && found < KK; base += 64) {
                int i = base + lane;
                bool v = (i < NPAIR) && !(fabsf(row[i] - row[i + 1]) > THRC);
                unsigned long long m = __ballot(v);
                while (m && found < KK) {
                    int l = __ffsll(m) - 1;
                    idxs[found] = base + l;
                    vflag[found] = 0.0f;
                    ++found;
                    m &= (m - 1);
                }
            }
        }
        if (lane < KK) {
            int i = idxs[lane];
            float uL = row[i];
            float uR = row[i + 1];
            float fc = (c[i] + c[i + 1]) * 0.5f;
            float* o = out + b * 48;
            o[16 + lane] = uL;
            o[24 + lane] = uR;
            o[32 + lane] = fc;
            o[40 + lane] = vflag[lane];
            ws_uLuR[(b * KK + lane) * 2 + 0] = uL;
            ws_uLuR[(b * KK + lane) * 2 + 1] = uR;
        }
    }

    int cnt = 0;
    const int base0 = p * 16384;
#pragma unroll
    for (int it = 0; it < 16; ++it) {
        int e0 = base0 + ((it << 8) + tid) * 4;
        float4 f = *(const float4*)(row + e0);
        cnt += (fabsf(f.x - f.y) > THRC);
        cnt += (fabsf(f.y - f.z) > THRC);
        cnt += (fabsf(f.z - f.w) > THRC);
        if (e0 + 4 < XN) {
            float e = row[e0 + 4];
            cnt += (fabsf(f.w - e) > THRC);
        }
    }
#pragma unroll
    for (int off = 32; off > 0; off >>= 1) cnt += __shfl_down(cnt, off, 64);
    if (lane == 0) sred[wave] = cnt;
    __syncthreads();
    if (tid == 0) ws_cnt[blockIdx.x] = sred[0] + sred[1] + sred[2] + sred[3];
}

// ---------------- Kernel 2: fused MLP, full-K per-thread, prefetched ---------
// 256 blocks x 512 threads; block = (row b, sub): 2 tokens.
// Thread owns whole output column(s); weights N-major (transposed) so the
// K-accumulation lives entirely in registers (no split-K partial phases for
// w1; 2-way for w2, 4-way for out_w1). Next phase's weight stream (32 uint4)
// is issued BEFORE the intervening barriers so the VMEM port stays busy
// through LN/combine phases.

// 8 K-steps x 2 tokens from one uint4 of bf16 against broadcast LDS z.
// zq: const float4* at the chunk's 8 float2 entries. 4 indep FMA chains.
#define DOT8(w, zq)                                                          \
    do {                                                                     \
        float4 q; unsigned int wu; float f0, f1;                             \
        q = (zq)[0]; wu = (w).x;                                             \
        f0 = __uint_as_float(wu << 16); f1 = __uint_as_float(wu & 0xffff0000u);\
        ax0 = fmaf(f0, q.x, ax0); ay0 = fmaf(f0, q.y, ay0);                  \
        ax1 = fmaf(f1, q.z, ax1); ay1 = fmaf(f1, q.w, ay1);                  \
        q = (zq)[1]; wu = (w).y;                                             \
        f0 = __uint_as_float(wu << 16); f1 = __uint_as_float(wu & 0xffff0000u);\
        ax0 = fmaf(f0, q.x, ax0); ay0 = fmaf(f0, q.y, ay0);                  \
        ax1 = fmaf(f1, q.z, ax1); ay1 = fmaf(f1, q.w, ay1);                  \
        q = (zq)[2]; wu = (w).z;                                             \
        f0 = __uint_as_float(wu << 16); f1 = __uint_as_float(wu & 0xffff0000u);\
        ax0 = fmaf(f0, q.x, ax0); ay0 = fmaf(f0, q.y, ay0);                  \
        ax1 = fmaf(f1, q.z, ax1); ay1 = fmaf(f1, q.w, ay1);                  \
        q = (zq)[3]; wu = (w).w;                                             \
        f0 = __uint_as_float(wu << 16); f1 = __uint_as_float(wu & 0xffff0000u);\
        ax0 = fmaf(f0, q.x, ax0); ay0 = fmaf(f0, q.y, ay0);                  \
        ax1 = fmaf(f1, q.z, ax1); ay1 = fmaf(f1, q.w, ay1);                  \
    } while (0)

__global__ __launch_bounds__(512) void mlp_kernel(
    const float* __restrict__ ws_uLuR, const int* __restrict__ ws_cnt,
    const unsigned short* __restrict__ bw,
    const float* __restrict__ w_in, const float* __restrict__ b_in,
    const float* __restrict__ ln_in_g, const float* __restrict__ ln_in_b,
    const float* __restrict__ rb_ln_g, const float* __restrict__ rb_ln_b,
    const float* __restrict__ rb_b1, const float* __restrict__ rb_b2,
    const float* __restrict__ out_ln_g, const float* __restrict__ out_ln_b,
    const float* __restrict__ out_b1,
    const float* __restrict__ out_w2, const float* __restrict__ out_b2,
    float* __restrict__ out) {
    __shared__ float2 hsv[HD];
    __shared__ float2 ztv[HD];
    __shared__ float2 z2tv[2 * HD];
    __shared__ float2 z3tv[HD / 2];
    __shared__ float2 part2[2 * HD];    // w2 2-way split-K partials
    __shared__ float2 part3[4 * (HD/2)];// out_w1 4-way split-K partials
    __shared__ float red[8][2][2];
    __shared__ float stat[2][2];
    __shared__ float fin[2][4];

    const int tid = threadIdx.x;
    const int bid = blockIdx.x;
    const int b = bid >> 2;
    const int sub = bid & 3;
    const int wave = tid >> 6, lane = tid & 63;

    if (sub == 0 && wave == 0) {
        int v = (lane < 16) ? ws_cnt[b * 16 + lane] : 0;
#pragma unroll
        for (int off = 8; off > 0; off >>= 1) v += __shfl_down(v, off, 64);
        if (lane == 0) out[3072 + b] = (float)v;
    }

    // ---- input layer ----
    if (tid < HD) {
        const int c = tid;
        float fw[6];
#pragma unroll
        for (int f = 0; f < 6; ++f) fw[f] = w_in[f * HD + c];
        float bin = b_in[c];
        float2 hv;
        float* hvp = (float*)&hv;
#pragma unroll
        for (int j = 0; j < 2; ++j) {
            int tok = b * KK + sub * 2 + j;
            float uL = ws_uLuR[tok * 2 + 0];
            float uR = ws_uLuR[tok * 2 + 1];
            float dd = uL - uR;
            float sg = (dd > 0.0f) ? 1.0f : ((dd < 0.0f) ? -1.0f : 0.0f);
            hvp[j] = bin + uL * fw[0] + uR * fw[1] + dd * fw[2] +
                     fabsf(dd) * fw[3] + (uL + uR) * 0.5f * fw[4] + sg * fw[5];
        }
        hsv[c] = hv;
    }

    // ---- prefetch w1[0] (full K for col tid) ----
    uint4 wr[32];
    {
        const unsigned short* wp =
            bw + (((tid >> 6) * 32) * 512 + (tid & 63) * 8);
#pragma unroll
        for (int c = 0; c < 32; ++c) wr[c] = *(const uint4*)(wp + c * 512);
    }
    __syncthreads();

#define LN_STATS()                                                            \
    do {                                                                      \
        if (tid < HD) {                                                       \
            float2 h2 = hsv[tid];                                             \
            float s[2] = {h2.x, h2.y};                                        \
            float q[2] = {h2.x * h2.x, h2.y * h2.y};                          \
            for (int off = 32; off > 0; off >>= 1) {                          \
                _Pragma("unroll") for (int j = 0; j < 2; ++j) {               \
                    s[j] += __shfl_down(s[j], off, 64);                       \
                    q[j] += __shfl_down(q[j], off, 64);                       \
                }                                                             \
            }                                                                 \
            if (lane == 0) {                                                  \
                _Pragma("unroll") for (int j = 0; j < 2; ++j) {               \
                    red[wave][j][0] = s[j];                                   \
                    red[wave][j][1] = q[j];                                   \
                }                                                             \
            }                                                                 \
        }                                                                     \
        __syncthreads();                                                      \
        if (tid < 2) {                                                        \
            float ts = 0.0f, tq = 0.0f;                                       \
            _Pragma("unroll") for (int w = 0; w < 4; ++w) {                   \
                ts += red[w][tid][0];                                         \
                tq += red[w][tid][1];                                         \
            }                                                                 \
            float mu = ts * (1.0f / 256.0f);                                  \
            float vr = tq * (1.0f / 256.0f) - mu * mu;                        \
            stat[tid][0] = mu;                                                \
            stat[tid][1] = rsqrtf(vr + 1e-5f);                                \
        }                                                                     \
        __syncthreads();                                                      \
    } while (0)

    LN_STATS();
    if (tid < HD) {
        const int c = tid;
        float g = ln_in_g[c], be = ln_in_b[c];
        float2 hv = hsv[c];
        hv.x = gelu_f((hv.x - stat[0][0]) * stat[0][1] * g + be);
        hv.y = gelu_f((hv.y - stat[1][0]) * stat[1][1] * g + be);
        hsv[c] = hv;
    }
    __syncthreads();

    // ---- 3 residual blocks ----
    for (int i = 0; i < 3; ++i) {
        LN_STATS();
        if (tid < HD) {
            const int c = tid;
            float gg = rb_ln_g[i * HD + c], bb = rb_ln_b[i * HD + c];
            float2 hv = hsv[c], zv;
            zv.x = (hv.x - stat[0][0]) * stat[0][1] * gg + bb;
            zv.y = (hv.y - stat[1][0]) * stat[1][1] * gg + bb;
            ztv[c] = zv;
        }
        __syncthreads();

        // w1: col = tid (N=512), full K=256 in registers (prefetched in wr)
        {
            float ax0 = 0, ax1 = 0, ay0 = 0, ay1 = 0;
            const float* zb = (const float*)ztv;
#pragma unroll
            for (int c = 0; c < 32; ++c) {
                uint4 w = wr[c];
                const float4* zq = (const float4*)(zb + c * 16);
                DOT8(w, zq);
            }
            float b1v = rb_b1[i * 2 * HD + tid];
            float2 zv;
            zv.x = gelu_f(ax0 + ax1 + b1v);
            zv.y = gelu_f(ay0 + ay1 + b1v);
            z2tv[tid] = zv;
        }
        // prefetch w2[i] (col = tid&255, K-half = tid>>8)
        {
            const int col = tid & 255, kh = tid >> 8;
            const unsigned short* wp = bw + 393216 + (size_t)i * 131072 +
                (((col >> 6) * 64 + kh * 32) * 512 + (col & 63) * 8);
#pragma unroll
            for (int c = 0; c < 32; ++c) wr[c] = *(const uint4*)(wp + c * 512);
        }
        __syncthreads();

        // w2: col = tid&255, 2-way split-K, partials via LDS
        {
            const int kh = tid >> 8;
            float ax0 = 0, ax1 = 0, ay0 = 0, ay1 = 0;
            const float* zb = (const float*)(z2tv + kh * 256);
#pragma unroll
            for (int c = 0; c < 32; ++c) {
                uint4 w = wr[c];
                const float4* zq = (const float4*)(zb + c * 16);
                DOT8(w, zq);
            }
            float2 pv;
            pv.x = ax0 + ax1;
            pv.y = ay0 + ay1;
            part2[tid] = pv;
        }
        // prefetch next phase's weights
        if (i < 2) {
            const unsigned short* wp = bw + (size_t)(i + 1) * 131072 +
                (((tid >> 6) * 32) * 512 + (tid & 63) * 8);
#pragma unroll
            for (int c = 0; c < 32; ++c) wr[c] = *(const uint4*)(wp + c * 512);
        } else {
            const int col = tid & 127, kq = tid >> 7;
            const unsigned short* wp = bw + 786432 +
                (((col >> 6) * 32 + kq * 8) * 512 + (col & 63) * 8);
#pragma unroll
            for (int c = 0; c < 8; ++c) wr[c] = *(const uint4*)(wp + c * 512);
        }
        __syncthreads();
        if (tid < HD) {
            float2 p0 = part2[tid], p1 = part2[HD + tid];
            float bb = rb_b2[i * HD + tid];
            float2 hv = hsv[tid];
            hv.x += p0.x + p1.x + bb;
            hv.y += p0.y + p1.y + bb;
            hsv[tid] = hv;
        }
        __syncthreads();
    }

    // ---- output head ----
    LN_STATS();
    if (tid < HD) {
        const int c = tid;
        float gg = out_ln_g[c], bb = out_ln_b[c];
        float2 hv = hsv[c], zv;
        zv.x = (hv.x - stat[0][0]) * stat[0][1] * gg + bb;
        zv.y = (hv.y - stat[1][0]) * stat[1][1] * gg + bb;
        ztv[c] = zv;
    }
    __syncthreads();

    // out_w1: col = tid&127, 4-way split-K (wr[0..7] prefetched)
    {
        const int kq = tid >> 7;
        float ax0 = 0, ax1 = 0, ay0 = 0, ay1 = 0;
        const float* zb = (const float*)(ztv + kq * 64);
#pragma unroll
        for (int c = 0; c < 8; ++c) {
            uint4 w = wr[c];
            const float4* zq = (const float4*)(zb + c * 16);
            DOT8(w, zq);
        }
        float2 pv;
        pv.x = ax0 + ax1;
        pv.y = ay0 + ay1;
        part3[tid] = pv;
    }
    __syncthreads();
    if (tid < HD / 2) {
        float2 p0 = part3[tid], p1 = part3[128 + tid];
        float2 p2 = part3[256 + tid], p3 = part3[384 + tid];
        float bv = out_b1[tid];
        float2 zv;
        zv.x = gelu_f(p0.x + p1.x + p2.x + p3.x + bv);
        zv.y = gelu_f(p0.y + p1.y + p2.y + p3.y + bv);
        z3tv[tid] = zv;
    }
    __syncthreads();

    // out_w2: K=128 -> N=2 (fp32, tiny)
    if (tid < HD / 2) {
        float2 z = z3tv[tid];
        float w0 = out_w2[tid * 2 + 0];
        float w1v = out_w2[tid * 2 + 1];
        float p[4];
        p[0] = z.x * w0; p[1] = z.x * w1v;
        p[2] = z.y * w0; p[3] = z.y * w1v;
#pragma unroll
        for (int off = 32; off > 0; off >>= 1) {
#pragma unroll
            for (int u = 0; u < 4; ++u) p[u] += __shfl_down(p[u], off, 64);
        }
        if (lane == 0) {
#pragma unroll
            for (int u = 0; u < 4; ++u) fin[wave][u] = p[u];
        }
    }
    __syncthreads();
    if (tid < 4) {
        int j = tid >> 1;
        int o = tid & 1;
        float s = out_b2[o] + fin[0][tid] + fin[1][tid];
        out[b * 48 + o * 8 + sub * 2 + j] = s;
    }
}

extern "C" void kernel_launch(void* const* d_in, const int* in_sizes, int n_in,
                              void* d_out, int out_size, void* d_ws, size_t ws_size,
                              hipStream_t stream) {
    const float* x        = (const float*)d_in[0];
    const float* w_in     = (const float*)d_in[1];
    const float* b_in     = (const float*)d_in[2];
    const float* ln_in_g  = (const float*)d_in[3];
    const float* ln_in_b  = (const float*)d_in[4];
    const float* rb_ln_g  = (const float*)d_in[5];
    const float* rb_ln_b  = (const float*)d_in[6];
    const float* rb_w1    = (const float*)d_in[7];
    const float* rb_b1    = (const float*)d_in[8];
    const float* rb_w2    = (const float*)d_in[9];
    const float* rb_b2    = (const float*)d_in[10];
    const float* out_ln_g = (const float*)d_in[11];
    const float* out_ln_b = (const float*)d_in[12];
    const float* out_w1   = (const float*)d_in[13];
    const float* out_b1   = (const float*)d_in[14];
    const float* out_w2   = (const float*)d_in[15];
    const float* out_b2   = (const float*)d_in[16];

    float* out = (float*)d_out;
    float* wsf = (float*)d_ws;                        // uLuR pairs [0..1024)
    int* wsc = (int*)(wsf + 1024);                    // 1024 partial counts
    unsigned short* bw = (unsigned short*)(wsf + 2048);  // bf16 weights (1.6 MB)

    convert_kernel<<<400, 256, 0, stream>>>(rb_w1, rb_w2, out_w1, bw);
    count_select_kernel<<<BN * 16, 256, 0, stream>>>(x, out, wsf, wsc);
    mlp_kernel<<<BN * 4, 512, 0, stream>>>(
        wsf, wsc, bw, w_in, b_in, ln_in_g, ln_in_b, rb_ln_g, rb_ln_b,
        rb_b1, rb_b2, out_ln_g, out_ln_b, out_b1, out_w2, out_b2, out);
}

// Round 8
// 683.751 us; speedup vs baseline: 1.0007x; 1.0007x over previous
//
#include <hip/hip_runtime.h>
#include <hip/hip_bf16.h>
#include <math.h>

#define XN 262144
#define NPAIR (XN - 1)
#define BN 64
#define HD 256
#define KK 8
#define THRC 1e-6f

__device__ __forceinline__ float gelu_f(float x) {
    return 0.5f * x * (1.0f + erff(x * 0.70710678118654752440f));
}

__device__ __forceinline__ unsigned short f2bf(float f) {
    unsigned int x = __float_as_uint(f);
    unsigned int r = (x + 0x7fffu + ((x >> 16) & 1u)) >> 16;  // RNE
    return (unsigned short)r;
}

// ---------------- Kernel 0: weights fp32 -> bf16, TRANSPOSED + lane-blocked --
// Layout per matrix (ushort idx): addr(n,c) = ((n>>6)*NC + c)*512 + (n&63)*8
// where c indexes 8-element K-chunks (NC = K/8). A wave of 64 consecutive
// cols loading chunk c reads 1 KB contiguous -> fully coalesced.
// Regions: [0) rb_w1T i=0..2 (NC=32, N=512, 131072 each) | [393216) rb_w2T
// (NC=64, N=256) | [786432) out_w1T (NC=32, N=128) | end 819200.
__global__ __launch_bounds__(256) void convert_kernel(
    const float* __restrict__ rb_w1, const float* __restrict__ rb_w2,
    const float* __restrict__ out_w1, unsigned short* __restrict__ bw) {
    int t = blockIdx.x * 256 + threadIdx.x;
    const float* s;
    int stride;
    unsigned short* d;
    if (t < 49152) {
        int i = t / 16384, r = t % 16384;
        int c = r >> 9, n = r & 511;  // c in [0,32), n in [0,512)
        s = rb_w1 + (size_t)i * 131072 + (size_t)c * 8 * 512 + n;
        stride = 512;
        d = bw + (size_t)i * 131072 + (((n >> 6) * 32 + c) * 512 + (n & 63) * 8);
    } else if (t < 98304) {
        int t2 = t - 49152;
        int i = t2 / 16384, r = t2 % 16384;
        int c = r >> 8, n = r & 255;  // c in [0,64), n in [0,256)
        s = rb_w2 + (size_t)i * 131072 + (size_t)c * 8 * 256 + n;
        stride = 256;
        d = bw + 393216 + (size_t)i * 131072 +
            (((n >> 6) * 64 + c) * 512 + (n & 63) * 8);
    } else {
        int r = t - 98304;            // [0,4096)
        int c = r >> 7, n = r & 127;  // c in [0,32), n in [0,128)
        s = out_w1 + (size_t)c * 8 * 128 + n;
        stride = 128;
        d = bw + 786432 + (((n >> 6) * 32 + c) * 512 + (n & 63) * 8);
    }
    union { unsigned short u[8]; uint4 v; } rr;
#pragma unroll
    for (int j = 0; j < 8; ++j) rr.u[j] = f2bf(s[j * stride]);
    *(uint4*)d = rr.v;
}

// ---------------- Kernel 1: fused count + first-8 select ---------------------
__global__ __launch_bounds__(256) void count_select_kernel(
    const float* __restrict__ x, float* __restrict__ out,
    float* __restrict__ ws_uLuR, int* __restrict__ ws_cnt) {
    __shared__ int sred[4];
    const int b = blockIdx.x >> 4;
    const int p = blockIdx.x & 15;
    const float* row = x + (size_t)b * 2 * XN;
    const int tid = threadIdx.x;
    const int lane = tid & 63, wave = tid >> 6;

    if (p == 0 && tid < 64) {
        const float* c = row + XN;
        int idxs[KK];
        float vflag[KK];
        int found = 0;
        for (int base = 0; base < NPAIR && found < KK; base += 64) {
            int i = base + lane;
            bool v = (i < NPAIR) && (fabsf(row[i] - row[i + 1]) > THRC);
            unsigned long long m = __ballot(v);
            while (m && found < KK) {
                int l = __ffsll(m) - 1;
                idxs[found] = base + l;
                vflag[found] = 1.0f;
                ++found;
                m &= (m - 1);
            }
        }
        if (found < KK) {
            for (int base = 0; base < NPAIR && found < KK; base += 64) {
                int i = base + lane;
                bool v = (i < NPAIR) && !(fabsf(row[i] - row[i + 1]) > THRC);
                unsigned long long m = __ballot(v);
                while (m && found < KK) {
                    int l = __ffsll(m) - 1;
                    idxs[found] = base + l;
                    vflag[found] = 0.0f;
                    ++found;
                    m &= (m - 1);
                }
            }
        }
        if (lane < KK) {
            int i = idxs[lane];
            float uL = row[i];
            float uR = row[i + 1];
            float fc = (c[i] + c[i + 1]) * 0.5f;
            float* o = out + b * 48;
            o[16 + lane] = uL;
            o[24 + lane] = uR;
            o[32 + lane] = fc;
            o[40 + lane] = vflag[lane];
            ws_uLuR[(b * KK + lane) * 2 + 0] = uL;
            ws_uLuR[(b * KK + lane) * 2 + 1] = uR;
        }
    }

    int cnt = 0;
    const int base0 = p * 16384;
#pragma unroll
    for (int it = 0; it < 16; ++it) {
        int e0 = base0 + ((it << 8) + tid) * 4;
        float4 f = *(const float4*)(row + e0);
        cnt += (fabsf(f.x - f.y) > THRC);
        cnt += (fabsf(f.y - f.z) > THRC);
        cnt += (fabsf(f.z - f.w) > THRC);
        if (e0 + 4 < XN) {
            float e = row[e0 + 4];
            cnt += (fabsf(f.w - e) > THRC);
        }
    }
#pragma unroll
    for (int off = 32; off > 0; off >>= 1) cnt += __shfl_down(cnt, off, 64);
    if (lane == 0) sred[wave] = cnt;
    __syncthreads();
    if (tid == 0) ws_cnt[blockIdx.x] = sred[0] + sred[1] + sred[2] + sred[3];
}

// ---------------- Kernel 2: fused MLP, full-K per-thread, prefetched ---------
// 256 blocks x 512 threads; block = (row b, sub): 2 tokens.
// __launch_bounds__(512, 2): exactly 1 block/CU, VGPR cap 256 so the 32-uint4
// cross-barrier weight prefetch (128 VGPRs) does NOT spill (R7 lesson: at the
// default 128-VGPR cap this spilled 1.36 GB to scratch).

// 8 K-steps x 2 tokens from one uint4 of bf16 against broadcast LDS z.
#define DOT8(w, zq)                                                          \
    do {                                                                     \
        float4 q; unsigned int wu; float f0, f1;                             \
        q = (zq)[0]; wu = (w).x;                                             \
        f0 = __uint_as_float(wu << 16); f1 = __uint_as_float(wu & 0xffff0000u);\
        ax0 = fmaf(f0, q.x, ax0); ay0 = fmaf(f0, q.y, ay0);                  \
        ax1 = fmaf(f1, q.z, ax1); ay1 = fmaf(f1, q.w, ay1);                  \
        q = (zq)[1]; wu = (w).y;                                             \
        f0 = __uint_as_float(wu << 16); f1 = __uint_as_float(wu & 0xffff0000u);\
        ax0 = fmaf(f0, q.x, ax0); ay0 = fmaf(f0, q.y, ay0);                  \
        ax1 = fmaf(f1, q.z, ax1); ay1 = fmaf(f1, q.w, ay1);                  \
        q = (zq)[2]; wu = (w).z;                                             \
        f0 = __uint_as_float(wu << 16); f1 = __uint_as_float(wu & 0xffff0000u);\
        ax0 = fmaf(f0, q.x, ax0); ay0 = fmaf(f0, q.y, ay0);                  \
        ax1 = fmaf(f1, q.z, ax1); ay1 = fmaf(f1, q.w, ay1);                  \
        q = (zq)[3]; wu = (w).w;                                             \
        f0 = __uint_as_float(wu << 16); f1 = __uint_as_float(wu & 0xffff0000u);\
        ax0 = fmaf(f0, q.x, ax0); ay0 = fmaf(f0, q.y, ay0);                  \
        ax1 = fmaf(f1, q.z, ax1); ay1 = fmaf(f1, q.w, ay1);                  \
    } while (0)

__global__ __launch_bounds__(512, 2) void mlp_kernel(
    const float* __restrict__ ws_uLuR, const int* __restrict__ ws_cnt,
    const unsigned short* __restrict__ bw,
    const float* __restrict__ w_in, const float* __restrict__ b_in,
    const float* __restrict__ ln_in_g, const float* __restrict__ ln_in_b,
    const float* __restrict__ rb_ln_g, const float* __restrict__ rb_ln_b,
    const float* __restrict__ rb_b1, const float* __restrict__ rb_b2,
    const float* __restrict__ out_ln_g, const float* __restrict__ out_ln_b,
    const float* __restrict__ out_b1,
    const float* __restrict__ out_w2, const float* __restrict__ out_b2,
    float* __restrict__ out) {
    __shared__ float2 hsv[HD];
    __shared__ float2 ztv[HD];
    __shared__ float2 z2tv[2 * HD];
    __shared__ float2 z3tv[HD / 2];
    __shared__ float2 part2[2 * HD];     // w2 2-way split-K partials
    __shared__ float2 part3[4 * (HD/2)]; // out_w1 4-way split-K partials
    __shared__ float red[8][2][2];
    __shared__ float stat[2][2];
    __shared__ float fin[2][4];

    const int tid = threadIdx.x;
    const int bid = blockIdx.x;
    const int b = bid >> 2;
    const int sub = bid & 3;
    const int wave = tid >> 6, lane = tid & 63;

    if (sub == 0 && wave == 0) {
        int v = (lane < 16) ? ws_cnt[b * 16 + lane] : 0;
#pragma unroll
        for (int off = 8; off > 0; off >>= 1) v += __shfl_down(v, off, 64);
        if (lane == 0) out[3072 + b] = (float)v;
    }

    // ---- input layer ----
    if (tid < HD) {
        const int c = tid;
        float fw[6];
#pragma unroll
        for (int f = 0; f < 6; ++f) fw[f] = w_in[f * HD + c];
        float bin = b_in[c];
        float2 hv;
        float* hvp = (float*)&hv;
#pragma unroll
        for (int j = 0; j < 2; ++j) {
            int tok = b * KK + sub * 2 + j;
            float uL = ws_uLuR[tok * 2 + 0];
            float uR = ws_uLuR[tok * 2 + 1];
            float dd = uL - uR;
            float sg = (dd > 0.0f) ? 1.0f : ((dd < 0.0f) ? -1.0f : 0.0f);
            hvp[j] = bin + uL * fw[0] + uR * fw[1] + dd * fw[2] +
                     fabsf(dd) * fw[3] + (uL + uR) * 0.5f * fw[4] + sg * fw[5];
        }
        hsv[c] = hv;
    }

    // ---- prefetch w1[0] (full K for col tid) ----
    uint4 wr[32];
    {
        const unsigned short* wp =
            bw + (((tid >> 6) * 32) * 512 + (tid & 63) * 8);
#pragma unroll
        for (int c = 0; c < 32; ++c) wr[c] = *(const uint4*)(wp + c * 512);
    }
    __syncthreads();

#define LN_STATS()                                                            \
    do {                                                                      \
        if (tid < HD) {                                                       \
            float2 h2 = hsv[tid];                                             \
            float s[2] = {h2.x, h2.y};                                        \
            float q[2] = {h2.x * h2.x, h2.y * h2.y};                          \
            for (int off = 32; off > 0; off >>= 1) {                          \
                _Pragma("unroll") for (int j = 0; j < 2; ++j) {               \
                    s[j] += __shfl_down(s[j], off, 64);                       \
                    q[j] += __shfl_down(q[j], off, 64);                       \
                }                                                             \
            }                                                                 \
            if (lane == 0) {                                                  \
                _Pragma("unroll") for (int j = 0; j < 2; ++j) {               \
                    red[wave][j][0] = s[j];                                   \
                    red[wave][j][1] = q[j];                                   \
                }                                                             \
            }                                                                 \
        }                                                                     \
        __syncthreads();                                                      \
        if (tid < 2) {                                                        \
            float ts = 0.0f, tq = 0.0f;                                       \
            _Pragma("unroll") for (int w = 0; w < 4; ++w) {                   \
                ts += red[w][tid][0];                                         \
                tq += red[w][tid][1];                                         \
            }                                                                 \
            float mu = ts * (1.0f / 256.0f);                                  \
            float vr = tq * (1.0f / 256.0f) - mu * mu;                        \
            stat[tid][0] = mu;                                                \
            stat[tid][1] = rsqrtf(vr + 1e-5f);                                \
        }                                                                     \
        __syncthreads();                                                      \
    } while (0)

    LN_STATS();
    if (tid < HD) {
        const int c = tid;
        float g = ln_in_g[c], be = ln_in_b[c];
        float2 hv = hsv[c];
        hv.x = gelu_f((hv.x - stat[0][0]) * stat[0][1] * g + be);
        hv.y = gelu_f((hv.y - stat[1][0]) * stat[1][1] * g + be);
        hsv[c] = hv;
    }
    __syncthreads();

    // ---- 3 residual blocks ----
    for (int i = 0; i < 3; ++i) {
        LN_STATS();
        if (tid < HD) {
            const int c = tid;
            float gg = rb_ln_g[i * HD + c], bb = rb_ln_b[i * HD + c];
            float2 hv = hsv[c], zv;
            zv.x = (hv.x - stat[0][0]) * stat[0][1] * gg + bb;
            zv.y = (hv.y - stat[1][0]) * stat[1][1] * gg + bb;
            ztv[c] = zv;
        }
        __syncthreads();

        // w1: col = tid (N=512), full K=256 in registers (prefetched in wr)
        {
            float ax0 = 0, ax1 = 0, ay0 = 0, ay1 = 0;
            const float* zb = (const float*)ztv;
#pragma unroll
            for (int c = 0; c < 32; ++c) {
                uint4 w = wr[c];
                const float4* zq = (const float4*)(zb + c * 16);
                DOT8(w, zq);
            }
            float b1v = rb_b1[i * 2 * HD + tid];
            float2 zv;
            zv.x = gelu_f(ax0 + ax1 + b1v);
            zv.y = gelu_f(ay0 + ay1 + b1v);
            z2tv[tid] = zv;
        }
        // prefetch w2[i] (col = tid&255, K-half = tid>>8)
        {
            const int col = tid & 255, kh = tid >> 8;
            const unsigned short* wp = bw + 393216 + (size_t)i * 131072 +
                (((col >> 6) * 64 + kh * 32) * 512 + (col & 63) * 8);
#pragma unroll
            for (int c = 0; c < 32; ++c) wr[c] = *(const uint4*)(wp + c * 512);
        }
        __syncthreads();

        // w2: col = tid&255, 2-way split-K, partials via LDS
        {
            const int kh = tid >> 8;
            float ax0 = 0, ax1 = 0, ay0 = 0, ay1 = 0;
            const float* zb = (const float*)(z2tv + kh * 256);
#pragma unroll
            for (int c = 0; c < 32; ++c) {
                uint4 w = wr[c];
                const float4* zq = (const float4*)(zb + c * 16);
                DOT8(w, zq);
            }
            float2 pv;
            pv.x = ax0 + ax1;
            pv.y = ay0 + ay1;
            part2[tid] = pv;
        }
        // prefetch next phase's weights
        if (i < 2) {
            const unsigned short* wp = bw + (size_t)(i + 1) * 131072 +
                (((tid >> 6) * 32) * 512 + (tid & 63) * 8);
#pragma unroll
            for (int c = 0; c < 32; ++c) wr[c] = *(const uint4*)(wp + c * 512);
        } else {
            const int col = tid & 127, kq = tid >> 7;
            const unsigned short* wp = bw + 786432 +
                (((col >> 6) * 32 + kq * 8) * 512 + (col & 63) * 8);
#pragma unroll
            for (int c = 0; c < 8; ++c) wr[c] = *(const uint4*)(wp + c * 512);
        }
        __syncthreads();
        if (tid < HD) {
            float2 p0 = part2[tid], p1 = part2[HD + tid];
            float bb = rb_b2[i * HD + tid];
            float2 hv = hsv[tid];
            hv.x += p0.x + p1.x + bb;
            hv.y += p0.y + p1.y + bb;
            hsv[tid] = hv;
        }
        __syncthreads();
    }

    // ---- output head ----
    LN_STATS();
    if (tid < HD) {
        const int c = tid;
        float gg = out_ln_g[c], bb = out_ln_b[c];
        float2 hv = hsv[c], zv;
        zv.x = (hv.x - stat[0][0]) * stat[0][1] * gg + bb;
        zv.y = (hv.y - stat[1][0]) * stat[1][1] * gg + bb;
        ztv[c] = zv;
    }
    __syncthreads();

    // out_w1: col = tid&127, 4-way split-K (wr[0..7] prefetched)
    {
        const int kq = tid >> 7;
        float ax0 = 0, ax1 = 0, ay0 = 0, ay1 = 0;
        const float* zb = (const float*)(ztv + kq * 64);
#pragma unroll
        for (int c = 0; c < 8; ++c) {
            uint4 w = wr[c];
            const float4* zq = (const float4*)(zb + c * 16);
            DOT8(w, zq);
        }
        float2 pv;
        pv.x = ax0 + ax1;
        pv.y = ay0 + ay1;
        part3[tid] = pv;
    }
    __syncthreads();
    if (tid < HD / 2) {
        float2 p0 = part3[tid], p1 = part3[128 + tid];
        float2 p2 = part3[256 + tid], p3 = part3[384 + tid];
        float bv = out_b1[tid];
        float2 zv;
        zv.x = gelu_f(p0.x + p1.x + p2.x + p3.x + bv);
        zv.y = gelu_f(p0.y + p1.y + p2.y + p3.y + bv);
        z3tv[tid] = zv;
    }
    __syncthreads();

    // out_w2: K=128 -> N=2 (fp32, tiny)
    if (tid < HD / 2) {
        float2 z = z3tv[tid];
        float w0 = out_w2[tid * 2 + 0];
        float w1v = out_w2[tid * 2 + 1];
        float p[4];
        p[0] = z.x * w0; p[1] = z.x * w1v;
        p[2] = z.y * w0; p[3] = z.y * w1v;
#pragma unroll
        for (int off = 32; off > 0; off >>= 1) {
#pragma unroll
            for (int u = 0; u < 4; ++u) p[u] += __shfl_down(p[u], off, 64);
        }
        if (lane == 0) {
#pragma unroll
            for (int u = 0; u < 4; ++u) fin[wave][u] = p[u];
        }
    }
    __syncthreads();
    if (tid < 4) {
        int j = tid >> 1;
        int o = tid & 1;
        float s = out_b2[o] + fin[0][tid] + fin[1][tid];
        out[b * 48 + o * 8 + sub * 2 + j] = s;
    }
}

extern "C" void kernel_launch(void* const* d_in, const int* in_sizes, int n_in,
                              void* d_out, int out_size, void* d_ws, size_t ws_size,
                              hipStream_t stream) {
    const float* x        = (const float*)d_in[0];
    const float* w_in     = (const float*)d_in[1];
    const float* b_in     = (const float*)d_in[2];
    const float* ln_in_g  = (const float*)d_in[3];
    const float* ln_in_b  = (const float*)d_in[4];
    const float* rb_ln_g  = (const float*)d_in[5];
    const float* rb_ln_b  = (const float*)d_in[6];
    const float* rb_w1    = (const float*)d_in[7];
    const float* rb_b1    = (const float*)d_in[8];
    const float* rb_w2    = (const float*)d_in[9];
    const float* rb_b2    = (const float*)d_in[10];
    const float* out_ln_g = (const float*)d_in[11];
    const float* out_ln_b = (const float*)d_in[12];
    const float* out_w1   = (const float*)d_in[13];
    const float* out_b1   = (const float*)d_in[14];
    const float* out_w2   = (const float*)d_in[15];
    const float* out_b2   = (const float*)d_in[16];

    float* out = (float*)d_out;
    float* wsf = (float*)d_ws;                        // uLuR pairs [0..1024)
    int* wsc = (int*)(wsf + 1024);                    // 1024 partial counts
    unsigned short* bw = (unsigned short*)(wsf + 2048);  // bf16 weights (1.6 MB)

    convert_kernel<<<400, 256, 0, stream>>>(rb_w1, rb_w2, out_w1, bw);
    count_select_kernel<<<BN * 16, 256, 0, stream>>>(x, out, wsf, wsc);
    mlp_kernel<<<BN * 4, 512, 0, stream>>>(
        wsf, wsc, bw, w_in, b_in, ln_in_g, ln_in_b, rb_ln_g, rb_ln_b,
        rb_b1, rb_b2, out_ln_g, out_ln_b, out_b1, out_w2, out_b2, out);
}

// Round 9
// 680.118 us; speedup vs baseline: 1.0060x; 1.0053x over previous
//
#include <hip/hip_runtime.h>
#include <hip/hip_bf16.h>
#include <math.h>

#define XN 262144
#define NPAIR (XN - 1)
#define BN 64
#define HD 256
#define KK 8
#define THRC 1e-6f

__device__ __forceinline__ float gelu_f(float x) {
    return 0.5f * x * (1.0f + erff(x * 0.70710678118654752440f));
}

__device__ __forceinline__ unsigned short f2bf(float f) {
    unsigned int x = __float_as_uint(f);
    unsigned int r = (x + 0x7fffu + ((x >> 16) & 1u)) >> 16;  // RNE
    return (unsigned short)r;
}

// ---------------- Kernel 0: weights fp32 -> bf16, TRANSPOSED + lane-blocked --
// Layout per matrix (ushort idx): addr(n,c) = ((n>>6)*NC + c)*512 + (n&63)*8
// where c indexes 8-element K-chunks (NC = K/8). A wave of 64 consecutive
// cols loading chunk c reads 1 KB contiguous -> fully coalesced.
// Regions: [0) rb_w1T i=0..2 (NC=32, N=512, 131072 each) | [393216) rb_w2T
// (NC=64, N=256) | [786432) out_w1T (NC=32, N=128) | end 819200.
__global__ __launch_bounds__(256) void convert_kernel(
    const float* __restrict__ rb_w1, const float* __restrict__ rb_w2,
    const float* __restrict__ out_w1, unsigned short* __restrict__ bw) {
    int t = blockIdx.x * 256 + threadIdx.x;
    const float* s;
    int stride;
    unsigned short* d;
    if (t < 49152) {
        int i = t / 16384, r = t % 16384;
        int c = r >> 9, n = r & 511;  // c in [0,32), n in [0,512)
        s = rb_w1 + (size_t)i * 131072 + (size_t)c * 8 * 512 + n;
        stride = 512;
        d = bw + (size_t)i * 131072 + (((n >> 6) * 32 + c) * 512 + (n & 63) * 8);
    } else if (t < 98304) {
        int t2 = t - 49152;
        int i = t2 / 16384, r = t2 % 16384;
        int c = r >> 8, n = r & 255;  // c in [0,64), n in [0,256)
        s = rb_w2 + (size_t)i * 131072 + (size_t)c * 8 * 256 + n;
        stride = 256;
        d = bw + 393216 + (size_t)i * 131072 +
            (((n >> 6) * 64 + c) * 512 + (n & 63) * 8);
    } else {
        int r = t - 98304;            // [0,4096)
        int c = r >> 7, n = r & 127;  // c in [0,32), n in [0,128)
        s = out_w1 + (size_t)c * 8 * 128 + n;
        stride = 128;
        d = bw + 786432 + (((n >> 6) * 32 + c) * 512 + (n & 63) * 8);
    }
    union { unsigned short u[8]; uint4 v; } rr;
#pragma unroll
    for (int j = 0; j < 8; ++j) rr.u[j] = f2bf(s[j * stride]);
    *(uint4*)d = rr.v;
}

// ---------------- Kernel 1: fused count + first-8 select ---------------------
__global__ __launch_bounds__(256) void count_select_kernel(
    const float* __restrict__ x, float* __restrict__ out,
    float* __restrict__ ws_uLuR, int* __restrict__ ws_cnt) {
    __shared__ int sred[4];
    const int b = blockIdx.x >> 4;
    const int p = blockIdx.x & 15;
    const float* row = x + (size_t)b * 2 * XN;
    const int tid = threadIdx.x;
    const int lane = tid & 63, wave = tid >> 6;

    if (p == 0 && tid < 64) {
        const float* c = row + XN;
        int idxs[KK];
        float vflag[KK];
        int found = 0;
        for (int base = 0; base < NPAIR && found < KK; base += 64) {
            int i = base + lane;
            bool v = (i < NPAIR) && (fabsf(row[i] - row[i + 1]) > THRC);
            unsigned long long m = __ballot(v);
            while (m && found < KK) {
                int l = __ffsll(m) - 1;
                idxs[found] = base + l;
                vflag[found] = 1.0f;
                ++found;
                m &= (m - 1);
            }
        }
        if (found < KK) {
            for (int base = 0; base < NPAIR && found < KK; base += 64) {
                int i = base + lane;
                bool v = (i < NPAIR) && !(fabsf(row[i] - row[i + 1]) > THRC);
                unsigned long long m = __ballot(v);
                while (m && found < KK) {
                    int l = __ffsll(m) - 1;
                    idxs[found] = base + l;
                    vflag[found] = 0.0f;
                    ++found;
                    m &= (m - 1);
                }
            }
        }
        if (lane < KK) {
            int i = idxs[lane];
            float uL = row[i];
            float uR = row[i + 1];
            float fc = (c[i] + c[i + 1]) * 0.5f;
            float* o = out + b * 48;
            o[16 + lane] = uL;
            o[24 + lane] = uR;
            o[32 + lane] = fc;
            o[40 + lane] = vflag[lane];
            ws_uLuR[(b * KK + lane) * 2 + 0] = uL;
            ws_uLuR[(b * KK + lane) * 2 + 1] = uR;
        }
    }

    int cnt = 0;
    const int base0 = p * 16384;
#pragma unroll
    for (int it = 0; it < 16; ++it) {
        int e0 = base0 + ((it << 8) + tid) * 4;
        float4 f = *(const float4*)(row + e0);
        cnt += (fabsf(f.x - f.y) > THRC);
        cnt += (fabsf(f.y - f.z) > THRC);
        cnt += (fabsf(f.z - f.w) > THRC);
        if (e0 + 4 < XN) {
            float e = row[e0 + 4];
            cnt += (fabsf(f.w - e) > THRC);
        }
    }
#pragma unroll
    for (int off = 32; off > 0; off >>= 1) cnt += __shfl_down(cnt, off, 64);
    if (lane == 0) sred[wave] = cnt;
    __syncthreads();
    if (tid == 0) ws_cnt[blockIdx.x] = sred[0] + sred[1] + sred[2] + sred[3];
}

// ---------------- Kernel 2: fused MLP, full-K per-thread, prefetched ---------
// 256 blocks x 512 threads; block = (row b, sub): 2 tokens.
// amdgpu_waves_per_eu(2,2): forces the allocator to assume exactly 2 waves/EU
// (1 block/CU) -> VGPR budget >=256, so the 32-uint4 cross-barrier weight
// prefetch (128 VGPRs) does NOT spill. R8 lesson: __launch_bounds__(512,2)
// sets only the MINIMUM waves/EU; allocator still targeted 4 waves/EU (128
// VGPRs) and spilled 1.36 GB to scratch.

// 8 K-steps x 2 tokens from one uint4 of bf16 against broadcast LDS z.
#define DOT8(w, zq)                                                          \
    do {                                                                     \
        float4 q; unsigned int wu; float f0, f1;                             \
        q = (zq)[0]; wu = (w).x;                                             \
        f0 = __uint_as_float(wu << 16); f1 = __uint_as_float(wu & 0xffff0000u);\
        ax0 = fmaf(f0, q.x, ax0); ay0 = fmaf(f0, q.y, ay0);                  \
        ax1 = fmaf(f1, q.z, ax1); ay1 = fmaf(f1, q.w, ay1);                  \
        q = (zq)[1]; wu = (w).y;                                             \
        f0 = __uint_as_float(wu << 16); f1 = __uint_as_float(wu & 0xffff0000u);\
        ax0 = fmaf(f0, q.x, ax0); ay0 = fmaf(f0, q.y, ay0);                  \
        ax1 = fmaf(f1, q.z, ax1); ay1 = fmaf(f1, q.w, ay1);                  \
        q = (zq)[2]; wu = (w).z;                                             \
        f0 = __uint_as_float(wu << 16); f1 = __uint_as_float(wu & 0xffff0000u);\
        ax0 = fmaf(f0, q.x, ax0); ay0 = fmaf(f0, q.y, ay0);                  \
        ax1 = fmaf(f1, q.z, ax1); ay1 = fmaf(f1, q.w, ay1);                  \
        q = (zq)[3]; wu = (w).w;                                             \
        f0 = __uint_as_float(wu << 16); f1 = __uint_as_float(wu & 0xffff0000u);\
        ax0 = fmaf(f0, q.x, ax0); ay0 = fmaf(f0, q.y, ay0);                  \
        ax1 = fmaf(f1, q.z, ax1); ay1 = fmaf(f1, q.w, ay1);                  \
    } while (0)

__global__ __launch_bounds__(512)
__attribute__((amdgpu_waves_per_eu(2, 2)))
void mlp_kernel(
    const float* __restrict__ ws_uLuR, const int* __restrict__ ws_cnt,
    const unsigned short* __restrict__ bw,
    const float* __restrict__ w_in, const float* __restrict__ b_in,
    const float* __restrict__ ln_in_g, const float* __restrict__ ln_in_b,
    const float* __restrict__ rb_ln_g, const float* __restrict__ rb_ln_b,
    const float* __restrict__ rb_b1, const float* __restrict__ rb_b2,
    const float* __restrict__ out_ln_g, const float* __restrict__ out_ln_b,
    const float* __restrict__ out_b1,
    const float* __restrict__ out_w2, const float* __restrict__ out_b2,
    float* __restrict__ out) {
    __shared__ float2 hsv[HD];
    __shared__ float2 ztv[HD];
    __shared__ float2 z2tv[2 * HD];
    __shared__ float2 z3tv[HD / 2];
    __shared__ float2 part2[2 * HD];     // w2 2-way split-K partials
    __shared__ float2 part3[4 * (HD/2)]; // out_w1 4-way split-K partials
    __shared__ float red[8][2][2];
    __shared__ float stat[2][2];
    __shared__ float fin[2][4];

    const int tid = threadIdx.x;
    const int bid = blockIdx.x;
    const int b = bid >> 2;
    const int sub = bid & 3;
    const int wave = tid >> 6, lane = tid & 63;

    if (sub == 0 && wave == 0) {
        int v = (lane < 16) ? ws_cnt[b * 16 + lane] : 0;
#pragma unroll
        for (int off = 8; off > 0; off >>= 1) v += __shfl_down(v, off, 64);
        if (lane == 0) out[3072 + b] = (float)v;
    }

    // ---- input layer ----
    if (tid < HD) {
        const int c = tid;
        float fw[6];
#pragma unroll
        for (int f = 0; f < 6; ++f) fw[f] = w_in[f * HD + c];
        float bin = b_in[c];
        float2 hv;
        float* hvp = (float*)&hv;
#pragma unroll
        for (int j = 0; j < 2; ++j) {
            int tok = b * KK + sub * 2 + j;
            float uL = ws_uLuR[tok * 2 + 0];
            float uR = ws_uLuR[tok * 2 + 1];
            float dd = uL - uR;
            float sg = (dd > 0.0f) ? 1.0f : ((dd < 0.0f) ? -1.0f : 0.0f);
            hvp[j] = bin + uL * fw[0] + uR * fw[1] + dd * fw[2] +
                     fabsf(dd) * fw[3] + (uL + uR) * 0.5f * fw[4] + sg * fw[5];
        }
        hsv[c] = hv;
    }

    // ---- prefetch w1[0] (full K for col tid) ----
    uint4 wr[32];
    {
        const unsigned short* wp =
            bw + (((tid >> 6) * 32) * 512 + (tid & 63) * 8);
#pragma unroll
        for (int c = 0; c < 32; ++c) wr[c] = *(const uint4*)(wp + c * 512);
    }
    __syncthreads();

#define LN_STATS()                                                            \
    do {                                                                      \
        if (tid < HD) {                                                       \
            float2 h2 = hsv[tid];                                             \
            float s[2] = {h2.x, h2.y};                                        \
            float q[2] = {h2.x * h2.x, h2.y * h2.y};                          \
            for (int off = 32; off > 0; off >>= 1) {                          \
                _Pragma("unroll") for (int j = 0; j < 2; ++j) {               \
                    s[j] += __shfl_down(s[j], off, 64);                       \
                    q[j] += __shfl_down(q[j], off, 64);                       \
                }                                                             \
            }                                                                 \
            if (lane == 0) {                                                  \
                _Pragma("unroll") for (int j = 0; j < 2; ++j) {               \
                    red[wave][j][0] = s[j];                                   \
                    red[wave][j][1] = q[j];                                   \
                }                                                             \
            }                                                                 \
        }                                                                     \
        __syncthreads();                                                      \
        if (tid < 2) {                                                        \
            float ts = 0.0f, tq = 0.0f;                                       \
            _Pragma("unroll") for (int w = 0; w < 4; ++w) {                   \
                ts += red[w][tid][0];                                         \
                tq += red[w][tid][1];                                         \
            }                                                                 \
            float mu = ts * (1.0f / 256.0f);                                  \
            float vr = tq * (1.0f / 256.0f) - mu * mu;                        \
            stat[tid][0] = mu;                                                \
            stat[tid][1] = rsqrtf(vr + 1e-5f);                                \
        }                                                                     \
        __syncthreads();                                                      \
    } while (0)

    LN_STATS();
    if (tid < HD) {
        const int c = tid;
        float g = ln_in_g[c], be = ln_in_b[c];
        float2 hv = hsv[c];
        hv.x = gelu_f((hv.x - stat[0][0]) * stat[0][1] * g + be);
        hv.y = gelu_f((hv.y - stat[1][0]) * stat[1][1] * g + be);
        hsv[c] = hv;
    }
    __syncthreads();

    // ---- 3 residual blocks ----
    for (int i = 0; i < 3; ++i) {
        LN_STATS();
        if (tid < HD) {
            const int c = tid;
            float gg = rb_ln_g[i * HD + c], bb = rb_ln_b[i * HD + c];
            float2 hv = hsv[c], zv;
            zv.x = (hv.x - stat[0][0]) * stat[0][1] * gg + bb;
            zv.y = (hv.y - stat[1][0]) * stat[1][1] * gg + bb;
            ztv[c] = zv;
        }
        __syncthreads();

        // w1: col = tid (N=512), full K=256 in registers (prefetched in wr)
        {
            float ax0 = 0, ax1 = 0, ay0 = 0, ay1 = 0;
            const float* zb = (const float*)ztv;
#pragma unroll
            for (int c = 0; c < 32; ++c) {
                uint4 w = wr[c];
                const float4* zq = (const float4*)(zb + c * 16);
                DOT8(w, zq);
            }
            float b1v = rb_b1[i * 2 * HD + tid];
            float2 zv;
            zv.x = gelu_f(ax0 + ax1 + b1v);
            zv.y = gelu_f(ay0 + ay1 + b1v);
            z2tv[tid] = zv;
        }
        // prefetch w2[i] (col = tid&255, K-half = tid>>8)
        {
            const int col = tid & 255, kh = tid >> 8;
            const unsigned short* wp = bw + 393216 + (size_t)i * 131072 +
                (((col >> 6) * 64 + kh * 32) * 512 + (col & 63) * 8);
#pragma unroll
            for (int c = 0; c < 32; ++c) wr[c] = *(const uint4*)(wp + c * 512);
        }
        __syncthreads();

        // w2: col = tid&255, 2-way split-K, partials via LDS
        {
            const int kh = tid >> 8;
            float ax0 = 0, ax1 = 0, ay0 = 0, ay1 = 0;
            const float* zb = (const float*)(z2tv + kh * 256);
#pragma unroll
            for (int c = 0; c < 32; ++c) {
                uint4 w = wr[c];
                const float4* zq = (const float4*)(zb + c * 16);
                DOT8(w, zq);
            }
            float2 pv;
            pv.x = ax0 + ax1;
            pv.y = ay0 + ay1;
            part2[tid] = pv;
        }
        // prefetch next phase's weights
        if (i < 2) {
            const unsigned short* wp = bw + (size_t)(i + 1) * 131072 +
                (((tid >> 6) * 32) * 512 + (tid & 63) * 8);
#pragma unroll
            for (int c = 0; c < 32; ++c) wr[c] = *(const uint4*)(wp + c * 512);
        } else {
            const int col = tid & 127, kq = tid >> 7;
            const unsigned short* wp = bw + 786432 +
                (((col >> 6) * 32 + kq * 8) * 512 + (col & 63) * 8);
#pragma unroll
            for (int c = 0; c < 8; ++c) wr[c] = *(const uint4*)(wp + c * 512);
        }
        __syncthreads();
        if (tid < HD) {
            float2 p0 = part2[tid], p1 = part2[HD + tid];
            float bb = rb_b2[i * HD + tid];
            float2 hv = hsv[tid];
            hv.x += p0.x + p1.x + bb;
            hv.y += p0.y + p1.y + bb;
            hsv[tid] = hv;
        }
        __syncthreads();
    }

    // ---- output head ----
    LN_STATS();
    if (tid < HD) {
        const int c = tid;
        float gg = out_ln_g[c], bb = out_ln_b[c];
        float2 hv = hsv[c], zv;
        zv.x = (hv.x - stat[0][0]) * stat[0][1] * gg + bb;
        zv.y = (hv.y - stat[1][0]) * stat[1][1] * gg + bb;
        ztv[c] = zv;
    }
    __syncthreads();

    // out_w1: col = tid&127, 4-way split-K (wr[0..7] prefetched)
    {
        const int kq = tid >> 7;
        float ax0 = 0, ax1 = 0, ay0 = 0, ay1 = 0;
        const float* zb = (const float*)(ztv + kq * 64);
#pragma unroll
        for (int c = 0; c < 8; ++c) {
            uint4 w = wr[c];
            const float4* zq = (const float4*)(zb + c * 16);
            DOT8(w, zq);
        }
        float2 pv;
        pv.x = ax0 + ax1;
        pv.y = ay0 + ay1;
        part3[tid] = pv;
    }
    __syncthreads();
    if (tid < HD / 2) {
        float2 p0 = part3[tid], p1 = part3[128 + tid];
        float2 p2 = part3[256 + tid], p3 = part3[384 + tid];
        float bv = out_b1[tid];
        float2 zv;
        zv.x = gelu_f(p0.x + p1.x + p2.x + p3.x + bv);
        zv.y = gelu_f(p0.y + p1.y + p2.y + p3.y + bv);
        z3tv[tid] = zv;
    }
    __syncthreads();

    // out_w2: K=128 -> N=2 (fp32, tiny)
    if (tid < HD / 2) {
        float2 z = z3tv[tid];
        float w0 = out_w2[tid * 2 + 0];
        float w1v = out_w2[tid * 2 + 1];
        float p[4];
        p[0] = z.x * w0; p[1] = z.x * w1v;
        p[2] = z.y * w0; p[3] = z.y * w1v;
#pragma unroll
        for (int off = 32; off > 0; off >>= 1) {
#pragma unroll
            for (int u = 0; u < 4; ++u) p[u] += __shfl_down(p[u], off, 64);
        }
        if (lane == 0) {
#pragma unroll
            for (int u = 0; u < 4; ++u) fin[wave][u] = p[u];
        }
    }
    __syncthreads();
    if (tid < 4) {
        int j = tid >> 1;
        int o = tid & 1;
        float s = out_b2[o] + fin[0][tid] + fin[1][tid];
        out[b * 48 + o * 8 + sub * 2 + j] = s;
    }
}

extern "C" void kernel_launch(void* const* d_in, const int* in_sizes, int n_in,
                              void* d_out, int out_size, void* d_ws, size_t ws_size,
                              hipStream_t stream) {
    const float* x        = (const float*)d_in[0];
    const float* w_in     = (const float*)d_in[1];
    const float* b_in     = (const float*)d_in[2];
    const float* ln_in_g  = (const float*)d_in[3];
    const float* ln_in_b  = (const float*)d_in[4];
    const float* rb_ln_g  = (const float*)d_in[5];
    const float* rb_ln_b  = (const float*)d_in[6];
    const float* rb_w1    = (const float*)d_in[7];
    const float* rb_b1    = (const float*)d_in[8];
    const float* rb_w2    = (const float*)d_in[9];
    const float* rb_b2    = (const float*)d_in[10];
    const float* out_ln_g = (const float*)d_in[11];
    const float* out_ln_b = (const float*)d_in[12];
    const float* out_w1   = (const float*)d_in[13];
    const float* out_b1   = (const float*)d_in[14];
    const float* out_w2   = (const float*)d_in[15];
    const float* out_b2   = (const float*)d_in[16];

    float* out = (float*)d_out;
    float* wsf = (float*)d_ws;                        // uLuR pairs [0..1024)
    int* wsc = (int*)(wsf + 1024);                    // 1024 partial counts
    unsigned short* bw = (unsigned short*)(wsf + 2048);  // bf16 weights (1.6 MB)

    convert_kernel<<<400, 256, 0, stream>>>(rb_w1, rb_w2, out_w1, bw);
    count_select_kernel<<<BN * 16, 256, 0, stream>>>(x, out, wsf, wsc);
    mlp_kernel<<<BN * 4, 512, 0, stream>>>(
        wsf, wsc, bw, w_in, b_in, ln_in_g, ln_in_b, rb_ln_g, rb_ln_b,
        rb_b1, rb_b2, out_ln_g, out_ln_b, out_b1, out_w2, out_b2, out);
}